// Round 4
// baseline (2798.880 us; speedup 1.0000x reference)
//
#include <hip/hip_runtime.h>
#include <cstdint>
#include <cstddef>

#define LL 1024
#define DD 1024
#define BB 16

static constexpr int BM = 128, BN = 128, BKT = 16;

// ---------------------------------------------------------------------------
// Weight transform: wk[(k*D + i)*D + o] = conv_w[o*D*3 + i*3 + k]
// ---------------------------------------------------------------------------
__global__ __launch_bounds__(256) void wk_kernel(const float* __restrict__ w,
                                                 float* __restrict__ wk) {
    int idx = blockIdx.x * 256 + threadIdx.x;
    if (idx >= 3 * DD * DD) return;
    int o = idx & 1023;
    int i = (idx >> 10) & 1023;
    int k = idx >> 20;
    wk[idx] = w[(size_t)o * 3072 + i * 3 + k];
}

// ---------------------------------------------------------------------------
// fp32 GEMM, 128x128 tile, BK=16, 256 threads, 8x8 micro-tile, global prefetch.
// mode 0 (conv): A is x (B,L,D) with causal shift. Row m=(b,l) from blockIdx.y;
//   K index j -> (k=j>>10, i=j&1023); A[m][j] = (l+k-2 >= 0) ? x[b][l+k-2][i] : 0.
//   (BK=16 tiles never straddle k since 16 | 1024.)  C row = m. N=1024.
// mode 1 (proj, L-chunked): blockIdx.y -> (bb = y/tpb, lt = y%tpb);
//   A row = bb*1024 + l0 + lt*128 + r (in nrm, ld=1024);
//   C row = bb*Lc + lt*128 + r (U chunk buffer, ld=N=3072).
// ---------------------------------------------------------------------------
__global__ __launch_bounds__(256) void gemm_kernel(const float* __restrict__ A,
                                                   const float* __restrict__ Bmat,
                                                   const float* __restrict__ bias,
                                                   float* __restrict__ C,
                                                   int N, int Kdim, int mode,
                                                   int l0, int tpb, int Lc) {
    __shared__ float As[BKT][BM];   // transposed: As[k][m]
    __shared__ float Bs[BKT][BN];   // Bs[k][n]
    const int tid = threadIdx.x;
    const int tx = tid & 15, ty = tid >> 4;
    const int n0 = blockIdx.x * BN;

    int arowbase, crowbase;
    if (mode == 0) {
        arowbase = blockIdx.y * BM;           // m0; b = m0>>10, l = m0&1023
        crowbase = arowbase;
    } else {
        int bb = blockIdx.y / tpb, lt = blockIdx.y - bb * tpb;
        arowbase = (bb << 10) + l0 + lt * BM;
        crowbase = bb * Lc + lt * BM;
    }

    const int arow = tid >> 1, acol = (tid & 1) << 3;   // A tile: 128 x 16
    const int brow = tid >> 4, bcol = (tid & 15) << 3;  // B tile: 16 x 128

    auto loadA = [&](int kt, float4& a0, float4& a1) {
        if (mode == 0) {
            int bb = arowbase >> 10, lrow = (arowbase & 1023) + arow;
            int k = kt >> 10, i0 = kt & 1023;
            int t = lrow + k - 2;                       // causal shift
            if (t < 0) {
                a0 = make_float4(0.f, 0.f, 0.f, 0.f);
                a1 = a0;
            } else {
                const float* pa = A + ((((size_t)(bb << 10)) + t) << 10) + i0 + acol;
                a0 = *(const float4*)pa;  a1 = *(const float4*)(pa + 4);
            }
        } else {
            const float* pa = A + ((size_t)(arowbase + arow) << 10) + kt + acol;
            a0 = *(const float4*)pa;  a1 = *(const float4*)(pa + 4);
        }
    };
    auto loadB = [&](int kt, float4& b0, float4& b1) {
        const float* pb = Bmat + (size_t)(kt + brow) * N + n0 + bcol;
        b0 = *(const float4*)pb;  b1 = *(const float4*)(pb + 4);
    };

    float acc[8][8];
#pragma unroll
    for (int i = 0; i < 8; ++i)
#pragma unroll
        for (int j = 0; j < 8; ++j) acc[i][j] = 0.f;

    float4 a0, a1, b0, b1;
    loadA(0, a0, a1);
    loadB(0, b0, b1);

    for (int kt = 0; kt < Kdim; kt += BKT) {
        As[acol + 0][arow] = a0.x; As[acol + 1][arow] = a0.y;
        As[acol + 2][arow] = a0.z; As[acol + 3][arow] = a0.w;
        As[acol + 4][arow] = a1.x; As[acol + 5][arow] = a1.y;
        As[acol + 6][arow] = a1.z; As[acol + 7][arow] = a1.w;
        *(float4*)&Bs[brow][bcol]     = b0;
        *(float4*)&Bs[brow][bcol + 4] = b1;
        __syncthreads();

        int kn = kt + BKT;
        if (kn < Kdim) {
            loadA(kn, a0, a1);
            loadB(kn, b0, b1);
        }

#pragma unroll
        for (int k = 0; k < BKT; ++k) {
            float a[8], bb[8];
            *(float4*)&a[0]  = *(const float4*)&As[k][ty * 8];
            *(float4*)&a[4]  = *(const float4*)&As[k][ty * 8 + 4];
            *(float4*)&bb[0] = *(const float4*)&Bs[k][tx * 8];
            *(float4*)&bb[4] = *(const float4*)&Bs[k][tx * 8 + 4];
#pragma unroll
            for (int i = 0; i < 8; ++i)
#pragma unroll
                for (int j = 0; j < 8; ++j)
                    acc[i][j] = fmaf(a[i], bb[j], acc[i][j]);
        }
        __syncthreads();
    }

    float bv[8];
#pragma unroll
    for (int j = 0; j < 8; ++j) bv[j] = bias ? bias[n0 + tx * 8 + j] : 0.f;
#pragma unroll
    for (int i = 0; i < 8; ++i) {
        float* crow = C + (size_t)(crowbase + ty * 8 + i) * N + n0 + tx * 8;
        float4 v0 = make_float4(acc[i][0] + bv[0], acc[i][1] + bv[1],
                                acc[i][2] + bv[2], acc[i][3] + bv[3]);
        float4 v1 = make_float4(acc[i][4] + bv[4], acc[i][5] + bv[5],
                                acc[i][6] + bv[6], acc[i][7] + bv[7]);
        *(float4*)crow       = v0;
        *(float4*)(crow + 4) = v1;
    }
}

// ---------------------------------------------------------------------------
// LayerNorm over D=1024. One block (256 threads, float4 each) per row.
// ---------------------------------------------------------------------------
__global__ __launch_bounds__(256) void ln_kernel(const float* __restrict__ in,
                                                 const float* __restrict__ g,
                                                 const float* __restrict__ be,
                                                 float* __restrict__ outp) {
    const int m = blockIdx.x;
    const int t = threadIdx.x;
    const float4 v = ((const float4*)(in + ((size_t)m << 10)))[t];
    float s = v.x + v.y + v.z + v.w;
    float q = v.x * v.x + v.y * v.y + v.z * v.z + v.w * v.w;
#pragma unroll
    for (int off = 32; off; off >>= 1) {
        s += __shfl_down(s, off);
        q += __shfl_down(q, off);
    }
    __shared__ float red[8];
    const int wv = t >> 6, ln = t & 63;
    if (ln == 0) { red[wv] = s; red[4 + wv] = q; }
    __syncthreads();
    float S = red[0] + red[1] + red[2] + red[3];
    float Q = red[4] + red[5] + red[6] + red[7];
    float mu  = S * (1.f / 1024.f);
    float var = Q * (1.f / 1024.f) - mu * mu;
    float inv = rsqrtf(var + 1e-5f);
    float4 g4  = ((const float4*)g)[t];
    float4 b4  = ((const float4*)be)[t];
    float4 o;
    o.x = (v.x - mu) * inv * g4.x + b4.x;
    o.y = (v.y - mu) * inv * g4.y + b4.y;
    o.z = (v.z - mu) * inv * g4.z + b4.z;
    o.w = (v.w - mu) * inv * g4.w + b4.w;
    ((float4*)(outp + ((size_t)m << 10)))[t] = o;
}

// ---------------------------------------------------------------------------
// SRU scan over one L-chunk [l0, l0+Lc). 16384 independent (b,d) recurrences;
// 256 blocks x 64 threads (full CU coverage every chunk). Carry c persisted in
// c_state between chunks. 8-deep double-buffered register prefetch.
// Fuses lambda mix: out = lw*cnn + (1-lw)*h.  nrm aliases outp (d_out reuse) —
// safe: reads of step l precede the write to step l (prefetch >= CH ahead) and
// each thread owns its (b,d) column exclusively.
// ---------------------------------------------------------------------------
__device__ __forceinline__ float sigmoid_f(float x) {
    return __builtin_amdgcn_rcpf(1.f + __expf(-x));
}
__device__ __forceinline__ float tanh_f(float x) {
    float e = __expf(2.f * x);                     // inf for large x -> t = 1
    return 1.f - 2.f * __builtin_amdgcn_rcpf(e + 1.f);
}

__global__ __launch_bounds__(64) void scan_kernel(const float* __restrict__ U,
                                                  const float* __restrict__ nrm,
                                                  const float* __restrict__ cnn,
                                                  const float* __restrict__ v_in,
                                                  const float* __restrict__ b_in,
                                                  const float* __restrict__ lam,
                                                  float* __restrict__ outp,
                                                  float* __restrict__ c_state,
                                                  int l0, int Lc) {
    const int tid = blockIdx.x * 64 + threadIdx.x;   // 0..16383
    const int b = tid >> 10, d = tid & 1023;
    const float vf = v_in[d], vr = v_in[DD + d];
    const float bf = b_in[d], br = b_in[DD + d];
    const float lw = lam[d];
    const float* Up = U + (size_t)b * Lc * 3072 + 3 * d;       // chunk-local rows
    const size_t rowbase = (((size_t)(b << 10) + l0) << 10) + d;
    const float* xp = nrm + rowbase;
    const float* cp = cnn + rowbase;
    float*       op = outp + rowbase;

    float c = (l0 == 0) ? 0.f : c_state[tid];
    constexpr int CH = 8;
    float A0[CH], A1[CH], A2[CH], AX[CH], AC[CH];
    float B0[CH], B1[CH], B2[CH], BX[CH], BC[CH];

#pragma unroll
    for (int j = 0; j < CH; ++j) {
        size_t lu = (size_t)j * 3072, lx = (size_t)j << 10;
        A0[j] = Up[lu]; A1[j] = Up[lu + 1]; A2[j] = Up[lu + 2];
        AX[j] = xp[lx]; AC[j] = cp[lx];
    }

    for (int ll0 = 0; ll0 < Lc; ll0 += 2 * CH) {
        // prefetch chunk B at ll0+CH
#pragma unroll
        for (int j = 0; j < CH; ++j) {
            int ll = ll0 + CH + j;
            size_t lu = (size_t)ll * 3072, lx = (size_t)ll << 10;
            B0[j] = Up[lu]; B1[j] = Up[lu + 1]; B2[j] = Up[lu + 2];
            BX[j] = xp[lx]; BC[j] = cp[lx];
        }
        // compute chunk A at ll0
#pragma unroll
        for (int j = 0; j < CH; ++j) {
            float f = sigmoid_f(A1[j] + vf * c + bf);
            float r = sigmoid_f(A2[j] + vr * c + br);
            float cn = fmaf(f, c - A0[j], A0[j]);        // f*c + (1-f)*u0
            float h  = r * tanh_f(cn) + (1.f - r) * AX[j];
            c = cn;
            op[(size_t)(ll0 + j) << 10] = fmaf(lw, AC[j] - h, h);
        }
        // prefetch chunk A at ll0+2*CH
        if (ll0 + 2 * CH < Lc) {
#pragma unroll
            for (int j = 0; j < CH; ++j) {
                int ll = ll0 + 2 * CH + j;
                size_t lu = (size_t)ll * 3072, lx = (size_t)ll << 10;
                A0[j] = Up[lu]; A1[j] = Up[lu + 1]; A2[j] = Up[lu + 2];
                AX[j] = xp[lx]; AC[j] = cp[lx];
            }
        }
        // compute chunk B at ll0+CH
#pragma unroll
        for (int j = 0; j < CH; ++j) {
            float f = sigmoid_f(B1[j] + vf * c + bf);
            float r = sigmoid_f(B2[j] + vr * c + br);
            float cn = fmaf(f, c - B0[j], B0[j]);
            float h  = r * tanh_f(cn) + (1.f - r) * BX[j];
            c = cn;
            op[(size_t)(ll0 + CH + j) << 10] = fmaf(lw, BC[j] - h, h);
        }
    }
    c_state[tid] = c;
}

// ---------------------------------------------------------------------------
// In-place RMSNorm over D=1024 on d_out.
// ---------------------------------------------------------------------------
__global__ __launch_bounds__(256) void rms_kernel(float* __restrict__ io,
                                                  const float* __restrict__ w) {
    const int m = blockIdx.x;
    const int t = threadIdx.x;
    float4 v = ((float4*)(io + ((size_t)m << 10)))[t];
    float q = v.x * v.x + v.y * v.y + v.z * v.z + v.w * v.w;
#pragma unroll
    for (int off = 32; off; off >>= 1) q += __shfl_down(q, off);
    __shared__ float red[4];
    const int wv = t >> 6, ln = t & 63;
    if (ln == 0) red[wv] = q;
    __syncthreads();
    float Q = red[0] + red[1] + red[2] + red[3];
    float inv = rsqrtf(Q * (1.f / 1024.f) + 1e-6f);
    float4 w4 = ((const float4*)w)[t];
    v.x *= inv * w4.x;
    v.y *= inv * w4.y;
    v.z *= inv * w4.z;
    v.w *= inv * w4.w;
    ((float4*)(io + ((size_t)m << 10)))[t] = v;
}

// ---------------------------------------------------------------------------
// Workspace (floats), adaptive to ws_size:
//   wk      : 3M (12.6 MB)
//   cnn     : 16M (67.1 MB)
//   c_state : 16K (64 KB)
//   U_buf   : 16*Lc*3072, Lc = largest of {1024,512,256,128} that fits
//             (1024 -> ~268 MB total, 512 -> ~172 MB, 256 -> ~124 MB,
//              128 -> ~101 MB).
// nrm lives in d_out.
// ---------------------------------------------------------------------------
extern "C" void kernel_launch(void* const* d_in, const int* in_sizes, int n_in,
                              void* d_out, int out_size, void* d_ws, size_t ws_size,
                              hipStream_t stream) {
    const float* x        = (const float*)d_in[0];
    const float* conv_w   = (const float*)d_in[1];
    const float* conv_b   = (const float*)d_in[2];
    const float* ln_g     = (const float*)d_in[3];
    const float* ln_b     = (const float*)d_in[4];
    const float* sru_w    = (const float*)d_in[5];
    const float* sru_v    = (const float*)d_in[6];
    const float* sru_b    = (const float*)d_in[7];
    const float* lambda_w = (const float*)d_in[8];
    const float* rms_w    = (const float*)d_in[9];
    float* out = (float*)d_out;

    const size_t ws_f = ws_size / 4;                   // floats available
    const size_t fixed = (size_t)3 * 1024 * 1024       // wk
                       + (size_t)16 * 1024 * 1024      // cnn
                       + 16384;                        // c_state
    int Lc = 128;
    for (int cand = 1024; cand >= 128; cand >>= 1) {
        if (fixed + (size_t)16 * cand * 3072 <= ws_f) { Lc = cand; break; }
    }
    const int tpb = Lc / 128;                          // 128-row tiles per batch

    float* ws      = (float*)d_ws;
    float* wk      = ws;                               // 3M floats
    float* cnn     = wk + (size_t)3 * 1024 * 1024;     // 16M floats
    float* c_state = cnn + (size_t)16 * 1024 * 1024;   // 16K floats
    float* U_buf   = c_state + 16384;                  // 16*Lc*3072 floats
    float* nrm     = out;                              // d_out doubles as scratch

    // 1. weight transform (O,I,K) -> (K,I,O)
    wk_kernel<<<dim3(12288), dim3(256), 0, stream>>>(conv_w, wk);
    // 2. conv as GEMM (causal pad fused): M=16384, K=3072, N=1024, + bias
    gemm_kernel<<<dim3(8, 128), dim3(256), 0, stream>>>(x, wk, conv_b, cnn,
                                                        1024, 3072, 0, 0, 0, 0);
    // 3. LayerNorm -> nrm (in d_out)
    ln_kernel<<<dim3(16384), dim3(256), 0, stream>>>(cnn, ln_g, ln_b, nrm);
    // 4+5. L-chunked: proj GEMM (M=16*Lc, K=1024, N=3072) then scan chunk
    for (int l0 = 0; l0 < LL; l0 += Lc) {
        gemm_kernel<<<dim3(24, 16 * tpb), dim3(256), 0, stream>>>(
            nrm, sru_w, nullptr, U_buf, 3072, 1024, 1, l0, tpb, Lc);
        scan_kernel<<<dim3(256), dim3(64), 0, stream>>>(
            U_buf, nrm, cnn, sru_v, sru_b, lambda_w, out, c_state, l0, Lc);
    }
    // 6. in-place RMSNorm
    rms_kernel<<<dim3(16384), dim3(256), 0, stream>>>(out, rms_w);
}

// Round 5
// 640.522 us; speedup vs baseline: 4.3697x; 4.3697x over previous
//
#include <hip/hip_runtime.h>
#include <cstdint>
#include <cstddef>

#define LL 1024
#define DD 1024
#define BB 16

typedef _Float16 f16;
typedef _Float16 f16x8 __attribute__((ext_vector_type(8)));
typedef _Float16 f16x4 __attribute__((ext_vector_type(4)));
typedef float f32x4 __attribute__((ext_vector_type(4)));

// ---------------------------------------------------------------------------
// x (f32) -> x_h (f16), vectorized
// ---------------------------------------------------------------------------
__global__ __launch_bounds__(256) void xsplit_kernel(const float* __restrict__ x,
                                                     f16* __restrict__ xh) {
    int i = blockIdx.x * 256 + threadIdx.x;          // float4 index
    const int total = BB * LL * DD / 4;
    if (i >= total) return;
    float4 v = ((const float4*)x)[i];
    f16x4 h;
    h[0] = (f16)v.x; h[1] = (f16)v.y; h[2] = (f16)v.z; h[3] = (f16)v.w;
    ((f16x4*)xh)[i] = h;
}

// ---------------------------------------------------------------------------
// conv_w (O,I,K) -> wkT f16 [N=O][Kdim = k*1024 + i]  (B^T layout, K contiguous)
// ---------------------------------------------------------------------------
__global__ __launch_bounds__(256) void wkt_kernel(const float* __restrict__ w,
                                                  f16* __restrict__ wkT) {
    int idx = blockIdx.x * 256 + threadIdx.x;
    if (idx >= 3 * DD * DD) return;
    int o = idx / 3072;
    int r = idx - o * 3072;
    int k = r >> 10, i = r & 1023;
    wkT[idx] = (f16)w[(size_t)o * 3072 + i * 3 + k];
}

// ---------------------------------------------------------------------------
// sru_w [D][3D] -> swT f16 [N=3D][K=D]  (B^T layout)
// ---------------------------------------------------------------------------
__global__ __launch_bounds__(256) void swt_kernel(const float* __restrict__ w,
                                                  f16* __restrict__ swT) {
    int idx = blockIdx.x * 256 + threadIdx.x;
    if (idx >= 3 * DD * DD) return;
    int e = idx >> 10, d = idx & 1023;
    swT[idx] = (f16)w[(size_t)d * 3072 + e];
}

// ---------------------------------------------------------------------------
// f16 MFMA GEMM: C[M][N] (f32) = A[M][K] * BT[N][K]^T (+bias), 128x128 tile,
// BK=64, 256 threads = 4 waves, each wave a 64x64 sub-tile via 4x4 fragments
// of v_mfma_f32_16x16x32_f16.
// LDS: A and B tiles both [128 rows][64 f16] (128B rows), XOR-swizzled
// (byte ^= (row&7)<<4) to kill the stride-128B ds_read_b128 bank conflict.
// mode 0 (conv): A = x_h (B,L,D) with causal shift: row m=(b,l), K idx
//   j -> (kc=j>>10, i=j&1023), elem = (l+kc-2 >= 0) ? x[b][l+kc-2][i] : 0.
//   (BK=64 | 1024 so a K-tile never straddles kc.)
// mode 1 (proj, L-chunked): blockIdx.y -> (bb = y/tpb, lt = y%tpb);
//   A row = bb*1024 + l0 + lt*128 + r; C row = bb*Lc + lt*128 + r.
// MFMA layouts: A lane l supplies A[row=l&15][k=(l>>4)*8+e]; B lane l supplies
// B[k=(l>>4)*8+e][col=l&15]; C/D lane l reg r -> row=(l>>4)*4+r, col=l&15
// (m89-verified). A/B share the same k-mapping assumption, so any k-order
// error cancels in the dot product.
// ---------------------------------------------------------------------------
__global__ __launch_bounds__(256) void hgemm_kernel(
    const f16* __restrict__ A, const f16* __restrict__ BT,
    const float* __restrict__ bias, float* __restrict__ C,
    int N, int Kdim, int mode, int l0, int tpb, int Lc) {
    __shared__ f16 Asm[128 * 64];
    __shared__ f16 Bsm[128 * 64];
    const int tid = threadIdx.x;
    const int lane = tid & 63, wave = tid >> 6;
    const int wm = wave & 1, wn = wave >> 1;         // wave tile origin
    const int n0 = blockIdx.x * 128;

    int arowbase, crowbase;
    if (mode == 0) {
        arowbase = blockIdx.y * 128;
        crowbase = arowbase;
    } else {
        int bb = blockIdx.y / tpb, lt = blockIdx.y - bb * tpb;
        arowbase = (bb << 10) + l0 + lt * 128;
        crowbase = bb * Lc + lt * 128;
    }

    // staging: 128 rows x 8 chunks(16B) per plane; thread -> row=tid>>1,
    // chunks scb..scb+3
    const int srow = tid >> 1;
    const int scb = (tid & 1) * 4;

    auto loadA = [&](int kt, f16x8 (&pa)[4]) {
#pragma unroll
        for (int q = 0; q < 4; ++q) {
            int sc = scb + q;
            if (mode == 0) {
                int m = arowbase + srow;
                int bb2 = m >> 10, l = m & 1023;
                int kc = kt >> 10;
                int t = l + kc - 2;                   // causal shift
                int i0 = (kt & 1023) + sc * 8;
                if (t < 0) {
                    f16x8 z;
#pragma unroll
                    for (int e = 0; e < 8; ++e) z[e] = (f16)0;
                    pa[q] = z;
                } else {
                    pa[q] = *(const f16x8*)(A + (((size_t)(bb2 << 10) + t) << 10) + i0);
                }
            } else {
                pa[q] = *(const f16x8*)(A + ((size_t)(arowbase + srow) << 10) + kt + sc * 8);
            }
        }
    };
    auto loadB = [&](int kt, f16x8 (&pb)[4]) {
#pragma unroll
        for (int q = 0; q < 4; ++q) {
            int sc = scb + q;
            pb[q] = *(const f16x8*)(BT + (size_t)(n0 + srow) * Kdim + kt + sc * 8);
        }
    };
    auto store_sm = [&](f16* sm, f16x8 (&p)[4]) {
#pragma unroll
        for (int q = 0; q < 4; ++q) {
            int sc = scb + q;
            int byte = srow * 128 + ((sc * 16) ^ ((srow & 7) << 4));
            *(f16x8*)((char*)sm + byte) = p[q];
        }
    };

    f32x4 acc[4][4];
#pragma unroll
    for (int i = 0; i < 4; ++i)
#pragma unroll
        for (int j = 0; j < 4; ++j)
#pragma unroll
            for (int r = 0; r < 4; ++r) acc[i][j][r] = 0.f;

    f16x8 pa[4], pb[4];
    loadA(0, pa);
    loadB(0, pb);

    const int kbyte = (lane >> 4) * 16;              // k-block byte offset
    const int rA = wm * 64 + (lane & 15);
    const int rB = wn * 64 + (lane & 15);

    for (int kt = 0; kt < Kdim; kt += 64) {
        store_sm(Asm, pa);
        store_sm(Bsm, pb);
        __syncthreads();
        if (kt + 64 < Kdim) {                        // prefetch next K-tile
            loadA(kt + 64, pa);
            loadB(kt + 64, pb);
        }
#pragma unroll
        for (int ks = 0; ks < 2; ++ks) {
            f16x8 a[4], b[4];
#pragma unroll
            for (int f = 0; f < 4; ++f) {
                int rowa = rA + f * 16;
                a[f] = *(const f16x8*)((const char*)Asm + rowa * 128 +
                                       ((ks * 64 + kbyte) ^ ((rowa & 7) << 4)));
                int rowb = rB + f * 16;
                b[f] = *(const f16x8*)((const char*)Bsm + rowb * 128 +
                                       ((ks * 64 + kbyte) ^ ((rowb & 7) << 4)));
            }
#pragma unroll
            for (int fi = 0; fi < 4; ++fi)
#pragma unroll
                for (int fj = 0; fj < 4; ++fj)
                    acc[fi][fj] = __builtin_amdgcn_mfma_f32_16x16x32_f16(
                        a[fi], b[fj], acc[fi][fj], 0, 0, 0);
        }
        __syncthreads();
    }

    // epilogue: C/D layout col=lane&15, row=(lane>>4)*4+r
    float bv[4];
#pragma unroll
    for (int fj = 0; fj < 4; ++fj)
        bv[fj] = bias ? bias[n0 + wn * 64 + fj * 16 + (lane & 15)] : 0.f;
#pragma unroll
    for (int fi = 0; fi < 4; ++fi) {
        int row0 = crowbase + wm * 64 + fi * 16 + ((lane >> 4) << 2);
#pragma unroll
        for (int fj = 0; fj < 4; ++fj) {
            int col = n0 + wn * 64 + fj * 16 + (lane & 15);
            float* cp = C + (size_t)row0 * N + col;
#pragma unroll
            for (int r = 0; r < 4; ++r)
                cp[(size_t)r * N] = acc[fi][fj][r] + bv[fj];
        }
    }
}

// ---------------------------------------------------------------------------
// LayerNorm over D=1024, fused f16 mirror for the proj-GEMM A operand.
// One block (256 threads, float4 each) per row.
// ---------------------------------------------------------------------------
__global__ __launch_bounds__(256) void ln_kernel(const float* __restrict__ in,
                                                 const float* __restrict__ g,
                                                 const float* __restrict__ be,
                                                 float* __restrict__ outp,
                                                 f16* __restrict__ outh) {
    const int m = blockIdx.x;
    const int t = threadIdx.x;
    const float4 v = ((const float4*)(in + ((size_t)m << 10)))[t];
    float s = v.x + v.y + v.z + v.w;
    float q = v.x * v.x + v.y * v.y + v.z * v.z + v.w * v.w;
#pragma unroll
    for (int off = 32; off; off >>= 1) {
        s += __shfl_down(s, off);
        q += __shfl_down(q, off);
    }
    __shared__ float red[8];
    const int wv = t >> 6, ln = t & 63;
    if (ln == 0) { red[wv] = s; red[4 + wv] = q; }
    __syncthreads();
    float S = red[0] + red[1] + red[2] + red[3];
    float Q = red[4] + red[5] + red[6] + red[7];
    float mu  = S * (1.f / 1024.f);
    float var = Q * (1.f / 1024.f) - mu * mu;
    float inv = rsqrtf(var + 1e-5f);
    float4 g4  = ((const float4*)g)[t];
    float4 b4  = ((const float4*)be)[t];
    float4 o;
    o.x = (v.x - mu) * inv * g4.x + b4.x;
    o.y = (v.y - mu) * inv * g4.y + b4.y;
    o.z = (v.z - mu) * inv * g4.z + b4.z;
    o.w = (v.w - mu) * inv * g4.w + b4.w;
    ((float4*)(outp + ((size_t)m << 10)))[t] = o;
    f16x4 h;
    h[0] = (f16)o.x; h[1] = (f16)o.y; h[2] = (f16)o.z; h[3] = (f16)o.w;
    ((f16x4*)(outh + ((size_t)m << 10)))[t] = h;
}

// ---------------------------------------------------------------------------
// SRU scan over one L-chunk [l0, l0+Lc). 16384 independent (b,d) recurrences;
// 256 blocks x 64 threads. Carry persisted in c_state between chunks.
// 8-deep double-buffered register prefetch. Fuses lambda mix.
// nrm aliases outp (d_out reuse) — safe: reads of step l precede the write to
// step l and each thread owns its (b,d) column exclusively.
// ---------------------------------------------------------------------------
__device__ __forceinline__ float sigmoid_f(float x) {
    return __builtin_amdgcn_rcpf(1.f + __expf(-x));
}
__device__ __forceinline__ float tanh_f(float x) {
    float e = __expf(2.f * x);                     // inf for large x -> t = 1
    return 1.f - 2.f * __builtin_amdgcn_rcpf(e + 1.f);
}

__global__ __launch_bounds__(64) void scan_kernel(const float* __restrict__ U,
                                                  const float* __restrict__ nrm,
                                                  const float* __restrict__ cnn,
                                                  const float* __restrict__ v_in,
                                                  const float* __restrict__ b_in,
                                                  const float* __restrict__ lam,
                                                  float* __restrict__ outp,
                                                  float* __restrict__ c_state,
                                                  int l0, int Lc) {
    const int tid = blockIdx.x * 64 + threadIdx.x;   // 0..16383
    const int b = tid >> 10, d = tid & 1023;
    const float vf = v_in[d], vr = v_in[DD + d];
    const float bf = b_in[d], br = b_in[DD + d];
    const float lw = lam[d];
    const float* Up = U + (size_t)b * Lc * 3072 + 3 * d;       // chunk-local rows
    const size_t rowbase = (((size_t)(b << 10) + l0) << 10) + d;
    const float* xp = nrm + rowbase;
    const float* cp = cnn + rowbase;
    float*       op = outp + rowbase;

    float c = (l0 == 0) ? 0.f : c_state[tid];
    constexpr int CH = 8;
    float A0[CH], A1[CH], A2[CH], AX[CH], AC[CH];
    float B0[CH], B1[CH], B2[CH], BX[CH], BC[CH];

#pragma unroll
    for (int j = 0; j < CH; ++j) {
        size_t lu = (size_t)j * 3072, lx = (size_t)j << 10;
        A0[j] = Up[lu]; A1[j] = Up[lu + 1]; A2[j] = Up[lu + 2];
        AX[j] = xp[lx]; AC[j] = cp[lx];
    }

    for (int ll0 = 0; ll0 < Lc; ll0 += 2 * CH) {
#pragma unroll
        for (int j = 0; j < CH; ++j) {
            int ll = ll0 + CH + j;
            size_t lu = (size_t)ll * 3072, lx = (size_t)ll << 10;
            B0[j] = Up[lu]; B1[j] = Up[lu + 1]; B2[j] = Up[lu + 2];
            BX[j] = xp[lx]; BC[j] = cp[lx];
        }
#pragma unroll
        for (int j = 0; j < CH; ++j) {
            float f = sigmoid_f(A1[j] + vf * c + bf);
            float r = sigmoid_f(A2[j] + vr * c + br);
            float cn = fmaf(f, c - A0[j], A0[j]);        // f*c + (1-f)*u0
            float h  = r * tanh_f(cn) + (1.f - r) * AX[j];
            c = cn;
            op[(size_t)(ll0 + j) << 10] = fmaf(lw, AC[j] - h, h);
        }
        if (ll0 + 2 * CH < Lc) {
#pragma unroll
            for (int j = 0; j < CH; ++j) {
                int ll = ll0 + 2 * CH + j;
                size_t lu = (size_t)ll * 3072, lx = (size_t)ll << 10;
                A0[j] = Up[lu]; A1[j] = Up[lu + 1]; A2[j] = Up[lu + 2];
                AX[j] = xp[lx]; AC[j] = cp[lx];
            }
        }
#pragma unroll
        for (int j = 0; j < CH; ++j) {
            float f = sigmoid_f(B1[j] + vf * c + bf);
            float r = sigmoid_f(B2[j] + vr * c + br);
            float cn = fmaf(f, c - B0[j], B0[j]);
            float h  = r * tanh_f(cn) + (1.f - r) * BX[j];
            c = cn;
            op[(size_t)(ll0 + CH + j) << 10] = fmaf(lw, BC[j] - h, h);
        }
    }
    c_state[tid] = c;
}

// ---------------------------------------------------------------------------
// In-place RMSNorm over D=1024 on d_out.
// ---------------------------------------------------------------------------
__global__ __launch_bounds__(256) void rms_kernel(float* __restrict__ io,
                                                  const float* __restrict__ w) {
    const int m = blockIdx.x;
    const int t = threadIdx.x;
    float4 v = ((float4*)(io + ((size_t)m << 10)))[t];
    float q = v.x * v.x + v.y * v.y + v.z * v.z + v.w * v.w;
#pragma unroll
    for (int off = 32; off; off >>= 1) q += __shfl_down(q, off);
    __shared__ float red[4];
    const int wv = t >> 6, ln = t & 63;
    if (ln == 0) red[wv] = q;
    __syncthreads();
    float Q = red[0] + red[1] + red[2] + red[3];
    float inv = rsqrtf(Q * (1.f / 1024.f) + 1e-6f);
    float4 w4 = ((const float4*)w)[t];
    v.x *= inv * w4.x;
    v.y *= inv * w4.y;
    v.z *= inv * w4.z;
    v.w *= inv * w4.w;
    ((float4*)(io + ((size_t)m << 10)))[t] = v;
}

// ---------------------------------------------------------------------------
// Workspace layout:
//   f16 region (76 MiB): x_h 16M | nrm_h 16M | wkT 3M | swT 3M  (elements)
//   f32 region: cnn 16M | c_state 16K | U 16*Lc*3072
// Lc adaptive: {1024,512,256,128} -> total {348,248,197,172} MB.
// Known from round 4: ws_size >= 281 MB, so Lc >= 512 guaranteed.
// nrm f32 lives in d_out.
// ---------------------------------------------------------------------------
extern "C" void kernel_launch(void* const* d_in, const int* in_sizes, int n_in,
                              void* d_out, int out_size, void* d_ws, size_t ws_size,
                              hipStream_t stream) {
    const float* x        = (const float*)d_in[0];
    const float* conv_w   = (const float*)d_in[1];
    const float* conv_b   = (const float*)d_in[2];
    const float* ln_g     = (const float*)d_in[3];
    const float* ln_b     = (const float*)d_in[4];
    const float* sru_w    = (const float*)d_in[5];
    const float* sru_v    = (const float*)d_in[6];
    const float* sru_b    = (const float*)d_in[7];
    const float* lambda_w = (const float*)d_in[8];
    const float* rms_w    = (const float*)d_in[9];
    float* out = (float*)d_out;

    f16* x_h   = (f16*)d_ws;                              // 16M f16
    f16* nrm_h = x_h   + (size_t)16 * 1024 * 1024;        // 16M f16
    f16* wkT   = nrm_h + (size_t)16 * 1024 * 1024;        // 3M f16
    f16* swT   = wkT   + (size_t)3 * 1024 * 1024;         // 3M f16
    float* cnn     = (float*)(swT + (size_t)3 * 1024 * 1024);  // 16M f32
    float* c_state = cnn + (size_t)16 * 1024 * 1024;      // 16K f32
    float* U_buf   = c_state + 16384;

    const size_t fixed_bytes = (size_t)38 * 1024 * 1024 * 2      // f16 region
                             + ((size_t)16 * 1024 * 1024 + 16384) * 4;
    int Lc = 128;
    for (int cand = 1024; cand >= 128; cand >>= 1) {
        if (fixed_bytes + (size_t)16 * cand * 3072 * 4 <= ws_size) { Lc = cand; break; }
    }
    const int tpb = Lc / 128;
    float* nrm = out;                                     // d_out doubles as scratch

    // 1. prep: f16 casts / B^T transforms
    xsplit_kernel<<<dim3(16384), dim3(256), 0, stream>>>(x, x_h);
    wkt_kernel<<<dim3(12288), dim3(256), 0, stream>>>(conv_w, wkT);
    swt_kernel<<<dim3(12288), dim3(256), 0, stream>>>(sru_w, swT);
    // 2. conv as f16-MFMA GEMM (causal pad fused): M=16384, K=3072, N=1024
    hgemm_kernel<<<dim3(8, 128), dim3(256), 0, stream>>>(x_h, wkT, conv_b, cnn,
                                                         1024, 3072, 0, 0, 0, 0);
    // 3. LayerNorm -> nrm f32 (d_out) + nrm_h f16
    ln_kernel<<<dim3(16384), dim3(256), 0, stream>>>(cnn, ln_g, ln_b, nrm, nrm_h);
    // 4+5. L-chunked: proj GEMM (M=16*Lc, K=1024, N=3072) then scan chunk
    for (int l0 = 0; l0 < LL; l0 += Lc) {
        hgemm_kernel<<<dim3(24, 16 * tpb), dim3(256), 0, stream>>>(
            nrm_h, swT, nullptr, U_buf, 3072, 1024, 1, l0, tpb, Lc);
        scan_kernel<<<dim3(256), dim3(64), 0, stream>>>(
            U_buf, nrm, cnn, sru_v, sru_b, lambda_w, out, c_state, l0, Lc);
    }
    // 6. in-place RMSNorm
    rms_kernel<<<dim3(16384), dim3(256), 0, stream>>>(out, rms_w);
}

// Round 6
// 599.637 us; speedup vs baseline: 4.6676x; 1.0682x over previous
//
#include <hip/hip_runtime.h>
#include <cstdint>
#include <cstddef>

#define LL 1024
#define DD 1024
#define BB 16

typedef _Float16 f16;
typedef _Float16 f16x8 __attribute__((ext_vector_type(8)));
typedef _Float16 f16x4 __attribute__((ext_vector_type(4)));
typedef float f32x4 __attribute__((ext_vector_type(4)));

// ---------------------------------------------------------------------------
// x (f32) -> x_h (f16), vectorized
// ---------------------------------------------------------------------------
__global__ __launch_bounds__(256) void xsplit_kernel(const float* __restrict__ x,
                                                     f16* __restrict__ xh) {
    int i = blockIdx.x * 256 + threadIdx.x;          // float4 index
    const int total = BB * LL * DD / 4;
    if (i >= total) return;
    float4 v = ((const float4*)x)[i];
    f16x4 h;
    h[0] = (f16)v.x; h[1] = (f16)v.y; h[2] = (f16)v.z; h[3] = (f16)v.w;
    ((f16x4*)xh)[i] = h;
}

// ---------------------------------------------------------------------------
// conv_w (O,I,K) -> wkT f16 [N=O][Kdim = k*1024 + i]  (B^T layout, K contiguous)
// ---------------------------------------------------------------------------
__global__ __launch_bounds__(256) void wkt_kernel(const float* __restrict__ w,
                                                  f16* __restrict__ wkT) {
    int idx = blockIdx.x * 256 + threadIdx.x;
    if (idx >= 3 * DD * DD) return;
    int o = idx / 3072;
    int r = idx - o * 3072;
    int k = r >> 10, i = r & 1023;
    wkT[idx] = (f16)w[(size_t)o * 3072 + i * 3 + k];
}

// ---------------------------------------------------------------------------
// sru_w [D][3D] -> swT f16 [N=3D][K=D]  (B^T layout)
// ---------------------------------------------------------------------------
__global__ __launch_bounds__(256) void swt_kernel(const float* __restrict__ w,
                                                  f16* __restrict__ swT) {
    int idx = blockIdx.x * 256 + threadIdx.x;
    if (idx >= 3 * DD * DD) return;
    int e = idx >> 10, d = idx & 1023;
    swT[idx] = (f16)w[(size_t)d * 3072 + e];
}

// ---------------------------------------------------------------------------
// Zero page for the causal-pad rows (d_ws is poisoned 0xAA before every call).
// ---------------------------------------------------------------------------
__global__ __launch_bounds__(128) void zp_kernel(f16* __restrict__ zp) {
    zp[threadIdx.x] = (f16)0;                        // 128 f16 = 256 B
}

// ---------------------------------------------------------------------------
// f16 MFMA GEMM: C[M][N] (f32) = A[M][K] * BT[N][K]^T (+bias), 128x128 tile,
// BK=64, 256 threads = 4 waves, each wave a 64x64 sub-tile via 4x4 fragments
// of v_mfma_f32_16x16x32_f16.
//
// Staging: global_load_lds dwordx4 (16B/lane, 1 KiB/wave-instr), LDS
// double-buffered (2 x 32 KiB). LDS dest is LINEAR (wave-uniform base +
// lane*16); the XOR bank-swizzle (chunk ^= row&7, 16B chunks) is applied to
// the per-lane GLOBAL source address, and the same XOR on the ds_read side
// (rule #21: linear dest + inverse-swizzled source + swizzled read).
// Per K-tile: issue next tile's 8 wave-instrs -> compute current -> vmcnt(0)
// + barrier -> swap (T3-minimum 2-phase; m97-class structure, ~874 TF).
//
// mode 0 (conv): A = x_h (B,L,D) with causal shift: row m=(b,l), K idx
//   j -> (kc=j>>10, i=j&1023), elem = (l+kc-2 >= 0) ? x[b][l+kc-2][i] : 0.
//   t<0 rows redirect their source to the 256B zero page zp.
//   (BK=64 | 1024 so a K-tile never straddles kc; 128-row tiles never
//   straddle batches.)
// mode 1 (proj): blockIdx.y -> (bb = y/tpb, lt = y%tpb);
//   A row = bb*1024 + l0 + lt*128 + r; C row = bb*Lc + lt*128 + r.
//
// MFMA layouts: A lane l supplies A[row=l&15][k=(l>>4)*8+e]; B lane l
// supplies B[k=(l>>4)*8+e][col=l&15]; C/D lane l reg r -> row=(l>>4)*4+r,
// col=l&15 (m89-verified). A/B share the same k-mapping, so any k-order
// error cancels in the dot product.
// ---------------------------------------------------------------------------
__global__ __launch_bounds__(256) void hgemm_kernel(
    const f16* __restrict__ A, const f16* __restrict__ BT,
    const float* __restrict__ bias, float* __restrict__ C,
    const f16* __restrict__ zp,
    int N, int Kdim, int mode, int l0, int tpb, int Lc) {
    __shared__ f16 sm[2][2][128 * 64];               // [buf][A/B][row*64 + e]
    const int tid = threadIdx.x;
    const int lane = tid & 63, wave = tid >> 6;
    const int wm = wave & 1, wn = wave >> 1;         // wave tile origin
    const int n0 = blockIdx.x * 128;

    int arowbase, crowbase;
    if (mode == 0) {
        arowbase = blockIdx.y * 128;
        crowbase = arowbase;
    } else {
        int bb = blockIdx.y / tpb, lt = blockIdx.y - bb * tpb;
        arowbase = (bb << 10) + l0 + lt * 128;
        crowbase = bb * Lc + lt * 128;
    }

    // staging geometry: instr i of this wave covers rows wave*32+i*8 .. +8;
    // lane -> row = base + (lane>>3), chunk = lane&7 (16B chunks of the row).
    // Source chunk is XOR-swizzled so that after the linear LDS write,
    // lds[row][c] = global[row][c ^ (row&7)].
    auto stageA = [&](int kt, int buf) {
#pragma unroll
        for (int i = 0; i < 4; ++i) {
            int row = wave * 32 + i * 8 + (lane >> 3);
            int chunk = (lane & 7) ^ (row & 7);
            const f16* src;
            if (mode == 0) {
                int m = arowbase + row;
                int bb2 = m >> 10, l = m & 1023;
                int kc = kt >> 10;
                int t = l + kc - 2;                   // causal shift
                src = (t < 0) ? (zp + chunk * 8)
                              : (A + (((size_t)(bb2 << 10) + t) << 10) +
                                 (kt & 1023) + chunk * 8);
            } else {
                src = A + ((size_t)(arowbase + row) << 10) + kt + chunk * 8;
            }
            __builtin_amdgcn_global_load_lds(
                (const __attribute__((address_space(1))) void*)src,
                (__attribute__((address_space(3))) void*)&sm[buf][0][(wave * 32 + i * 8) * 64],
                16, 0, 0);
        }
    };
    auto stageB = [&](int kt, int buf) {
#pragma unroll
        for (int i = 0; i < 4; ++i) {
            int row = wave * 32 + i * 8 + (lane >> 3);
            int chunk = (lane & 7) ^ (row & 7);
            const f16* src = BT + (size_t)(n0 + row) * Kdim + kt + chunk * 8;
            __builtin_amdgcn_global_load_lds(
                (const __attribute__((address_space(1))) void*)src,
                (__attribute__((address_space(3))) void*)&sm[buf][1][(wave * 32 + i * 8) * 64],
                16, 0, 0);
        }
    };

    f32x4 acc[4][4];
#pragma unroll
    for (int i = 0; i < 4; ++i)
#pragma unroll
        for (int j = 0; j < 4; ++j)
#pragma unroll
            for (int r = 0; r < 4; ++r) acc[i][j][r] = 0.f;

    // prologue: stage tile 0 into buf 0
    stageA(0, 0);
    stageB(0, 0);
    asm volatile("s_waitcnt vmcnt(0)" ::: "memory");
    __syncthreads();

    const int kbyte = (lane >> 4) * 16;              // k-block byte offset
    const int rA = wm * 64 + (lane & 15);
    const int rB = wn * 64 + (lane & 15);

    int cur = 0;
    for (int kt = 0; kt < Kdim; kt += 64) {
        // issue next K-tile's staging into the other buffer (overlaps MFMA)
        if (kt + 64 < Kdim) {
            stageA(kt + 64, cur ^ 1);
            stageB(kt + 64, cur ^ 1);
        }
        const char* Ap = (const char*)&sm[cur][0][0];
        const char* Bp = (const char*)&sm[cur][1][0];
#pragma unroll
        for (int ks = 0; ks < 2; ++ks) {
            f16x8 a[4], b[4];
#pragma unroll
            for (int f = 0; f < 4; ++f) {
                int rowa = rA + f * 16;
                a[f] = *(const f16x8*)(Ap + rowa * 128 +
                                       ((ks * 64 + kbyte) ^ ((rowa & 7) << 4)));
                int rowb = rB + f * 16;
                b[f] = *(const f16x8*)(Bp + rowb * 128 +
                                       ((ks * 64 + kbyte) ^ ((rowb & 7) << 4)));
            }
#pragma unroll
            for (int fi = 0; fi < 4; ++fi)
#pragma unroll
                for (int fj = 0; fj < 4; ++fj)
                    acc[fi][fj] = __builtin_amdgcn_mfma_f32_16x16x32_f16(
                        a[fi], b[fj], acc[fi][fj], 0, 0, 0);
        }
        // drain next-tile staging, then all waves swap together
        asm volatile("s_waitcnt vmcnt(0)" ::: "memory");
        __syncthreads();
        cur ^= 1;
    }

    // epilogue: C/D layout col=lane&15, row=(lane>>4)*4+r
    float bv[4];
#pragma unroll
    for (int fj = 0; fj < 4; ++fj)
        bv[fj] = bias ? bias[n0 + wn * 64 + fj * 16 + (lane & 15)] : 0.f;
#pragma unroll
    for (int fi = 0; fi < 4; ++fi) {
        int row0 = crowbase + wm * 64 + fi * 16 + ((lane >> 4) << 2);
#pragma unroll
        for (int fj = 0; fj < 4; ++fj) {
            int col = n0 + wn * 64 + fj * 16 + (lane & 15);
            float* cp = C + (size_t)row0 * N + col;
#pragma unroll
            for (int r = 0; r < 4; ++r)
                cp[(size_t)r * N] = acc[fi][fj][r] + bv[fj];
        }
    }
}

// ---------------------------------------------------------------------------
// LayerNorm over D=1024, fused f16 mirror for the proj-GEMM A operand.
// One block (256 threads, float4 each) per row.
// ---------------------------------------------------------------------------
__global__ __launch_bounds__(256) void ln_kernel(const float* __restrict__ in,
                                                 const float* __restrict__ g,
                                                 const float* __restrict__ be,
                                                 float* __restrict__ outp,
                                                 f16* __restrict__ outh) {
    const int m = blockIdx.x;
    const int t = threadIdx.x;
    const float4 v = ((const float4*)(in + ((size_t)m << 10)))[t];
    float s = v.x + v.y + v.z + v.w;
    float q = v.x * v.x + v.y * v.y + v.z * v.z + v.w * v.w;
#pragma unroll
    for (int off = 32; off; off >>= 1) {
        s += __shfl_down(s, off);
        q += __shfl_down(q, off);
    }
    __shared__ float red[8];
    const int wv = t >> 6, ln = t & 63;
    if (ln == 0) { red[wv] = s; red[4 + wv] = q; }
    __syncthreads();
    float S = red[0] + red[1] + red[2] + red[3];
    float Q = red[4] + red[5] + red[6] + red[7];
    float mu  = S * (1.f / 1024.f);
    float var = Q * (1.f / 1024.f) - mu * mu;
    float inv = rsqrtf(var + 1e-5f);
    float4 g4  = ((const float4*)g)[t];
    float4 b4  = ((const float4*)be)[t];
    float4 o;
    o.x = (v.x - mu) * inv * g4.x + b4.x;
    o.y = (v.y - mu) * inv * g4.y + b4.y;
    o.z = (v.z - mu) * inv * g4.z + b4.z;
    o.w = (v.w - mu) * inv * g4.w + b4.w;
    ((float4*)(outp + ((size_t)m << 10)))[t] = o;
    f16x4 h;
    h[0] = (f16)o.x; h[1] = (f16)o.y; h[2] = (f16)o.z; h[3] = (f16)o.w;
    ((f16x4*)(outh + ((size_t)m << 10)))[t] = h;
}

// ---------------------------------------------------------------------------
// SRU scan over one L-chunk [l0, l0+Lc). 16384 independent (b,d) recurrences;
// 256 blocks x 64 threads. Carry persisted in c_state between chunks.
// 8-deep double-buffered register prefetch. Fuses lambda mix.
// nrm aliases outp (d_out reuse) — safe: reads of step l precede the write to
// step l and each thread owns its (b,d) column exclusively.
// ---------------------------------------------------------------------------
__device__ __forceinline__ float sigmoid_f(float x) {
    return __builtin_amdgcn_rcpf(1.f + __expf(-x));
}
__device__ __forceinline__ float tanh_f(float x) {
    float e = __expf(2.f * x);                     // inf for large x -> t = 1
    return 1.f - 2.f * __builtin_amdgcn_rcpf(e + 1.f);
}

__global__ __launch_bounds__(64) void scan_kernel(const float* __restrict__ U,
                                                  const float* __restrict__ nrm,
                                                  const float* __restrict__ cnn,
                                                  const float* __restrict__ v_in,
                                                  const float* __restrict__ b_in,
                                                  const float* __restrict__ lam,
                                                  float* __restrict__ outp,
                                                  float* __restrict__ c_state,
                                                  int l0, int Lc) {
    const int tid = blockIdx.x * 64 + threadIdx.x;   // 0..16383
    const int b = tid >> 10, d = tid & 1023;
    const float vf = v_in[d], vr = v_in[DD + d];
    const float bf = b_in[d], br = b_in[DD + d];
    const float lw = lam[d];
    const float* Up = U + (size_t)b * Lc * 3072 + 3 * d;       // chunk-local rows
    const size_t rowbase = (((size_t)(b << 10) + l0) << 10) + d;
    const float* xp = nrm + rowbase;
    const float* cp = cnn + rowbase;
    float*       op = outp + rowbase;

    float c = (l0 == 0) ? 0.f : c_state[tid];
    constexpr int CH = 8;
    float A0[CH], A1[CH], A2[CH], AX[CH], AC[CH];
    float B0[CH], B1[CH], B2[CH], BX[CH], BC[CH];

#pragma unroll
    for (int j = 0; j < CH; ++j) {
        size_t lu = (size_t)j * 3072, lx = (size_t)j << 10;
        A0[j] = Up[lu]; A1[j] = Up[lu + 1]; A2[j] = Up[lu + 2];
        AX[j] = xp[lx]; AC[j] = cp[lx];
    }

    for (int ll0 = 0; ll0 < Lc; ll0 += 2 * CH) {
#pragma unroll
        for (int j = 0; j < CH; ++j) {
            int ll = ll0 + CH + j;
            size_t lu = (size_t)ll * 3072, lx = (size_t)ll << 10;
            B0[j] = Up[lu]; B1[j] = Up[lu + 1]; B2[j] = Up[lu + 2];
            BX[j] = xp[lx]; BC[j] = cp[lx];
        }
#pragma unroll
        for (int j = 0; j < CH; ++j) {
            float f = sigmoid_f(A1[j] + vf * c + bf);
            float r = sigmoid_f(A2[j] + vr * c + br);
            float cn = fmaf(f, c - A0[j], A0[j]);        // f*c + (1-f)*u0
            float h  = r * tanh_f(cn) + (1.f - r) * AX[j];
            c = cn;
            op[(size_t)(ll0 + j) << 10] = fmaf(lw, AC[j] - h, h);
        }
        if (ll0 + 2 * CH < Lc) {
#pragma unroll
            for (int j = 0; j < CH; ++j) {
                int ll = ll0 + 2 * CH + j;
                size_t lu = (size_t)ll * 3072, lx = (size_t)ll << 10;
                A0[j] = Up[lu]; A1[j] = Up[lu + 1]; A2[j] = Up[lu + 2];
                AX[j] = xp[lx]; AC[j] = cp[lx];
            }
        }
#pragma unroll
        for (int j = 0; j < CH; ++j) {
            float f = sigmoid_f(B1[j] + vf * c + bf);
            float r = sigmoid_f(B2[j] + vr * c + br);
            float cn = fmaf(f, c - B0[j], B0[j]);
            float h  = r * tanh_f(cn) + (1.f - r) * BX[j];
            c = cn;
            op[(size_t)(ll0 + CH + j) << 10] = fmaf(lw, BC[j] - h, h);
        }
    }
    c_state[tid] = c;
}

// ---------------------------------------------------------------------------
// In-place RMSNorm over D=1024 on d_out.
// ---------------------------------------------------------------------------
__global__ __launch_bounds__(256) void rms_kernel(float* __restrict__ io,
                                                  const float* __restrict__ w) {
    const int m = blockIdx.x;
    const int t = threadIdx.x;
    float4 v = ((float4*)(io + ((size_t)m << 10)))[t];
    float q = v.x * v.x + v.y * v.y + v.z * v.z + v.w * v.w;
#pragma unroll
    for (int off = 32; off; off >>= 1) q += __shfl_down(q, off);
    __shared__ float red[4];
    const int wv = t >> 6, ln = t & 63;
    if (ln == 0) red[wv] = q;
    __syncthreads();
    float Q = red[0] + red[1] + red[2] + red[3];
    float inv = rsqrtf(Q * (1.f / 1024.f) + 1e-6f);
    float4 w4 = ((const float4*)w)[t];
    v.x *= inv * w4.x;
    v.y *= inv * w4.y;
    v.z *= inv * w4.z;
    v.w *= inv * w4.w;
    ((float4*)(io + ((size_t)m << 10)))[t] = v;
}

// ---------------------------------------------------------------------------
// Workspace layout:
//   f16 region: x_h 16M | nrm_h 16M | wkT 3M | swT 3M | zp 1K   (elements)
//   f32 region: cnn 16M | c_state 16K | U 16*Lc*3072
// Lc adaptive: {1024,512,256,128}. Round-5 evidence: Lc=1024 fit
// (ws_size >= ~348 MB). nrm f32 lives in d_out.
// ---------------------------------------------------------------------------
extern "C" void kernel_launch(void* const* d_in, const int* in_sizes, int n_in,
                              void* d_out, int out_size, void* d_ws, size_t ws_size,
                              hipStream_t stream) {
    const float* x        = (const float*)d_in[0];
    const float* conv_w   = (const float*)d_in[1];
    const float* conv_b   = (const float*)d_in[2];
    const float* ln_g     = (const float*)d_in[3];
    const float* ln_b     = (const float*)d_in[4];
    const float* sru_w    = (const float*)d_in[5];
    const float* sru_v    = (const float*)d_in[6];
    const float* sru_b    = (const float*)d_in[7];
    const float* lambda_w = (const float*)d_in[8];
    const float* rms_w    = (const float*)d_in[9];
    float* out = (float*)d_out;

    f16* x_h   = (f16*)d_ws;                              // 16M f16
    f16* nrm_h = x_h   + (size_t)16 * 1024 * 1024;        // 16M f16
    f16* wkT   = nrm_h + (size_t)16 * 1024 * 1024;        // 3M f16
    f16* swT   = wkT   + (size_t)3 * 1024 * 1024;         // 3M f16
    f16* zp    = swT   + (size_t)3 * 1024 * 1024;         // 1K f16 (zero page)
    float* cnn     = (float*)(zp + 1024);                 // 16M f32
    float* c_state = cnn + (size_t)16 * 1024 * 1024;      // 16K f32
    float* U_buf   = c_state + 16384;

    const size_t fixed_bytes = ((size_t)38 * 1024 * 1024 + 1024) * 2
                             + ((size_t)16 * 1024 * 1024 + 16384) * 4;
    int Lc = 128;
    for (int cand = 1024; cand >= 128; cand >>= 1) {
        if (fixed_bytes + (size_t)16 * cand * 3072 * 4 <= ws_size) { Lc = cand; break; }
    }
    const int tpb = Lc / 128;
    float* nrm = out;                                     // d_out doubles as scratch

    // 1. prep: f16 casts / B^T transforms / zero page
    xsplit_kernel<<<dim3(16384), dim3(256), 0, stream>>>(x, x_h);
    wkt_kernel<<<dim3(12288), dim3(256), 0, stream>>>(conv_w, wkT);
    swt_kernel<<<dim3(12288), dim3(256), 0, stream>>>(sru_w, swT);
    zp_kernel<<<dim3(1), dim3(128), 0, stream>>>(zp);
    // 2. conv as f16-MFMA GEMM (causal pad fused): M=16384, K=3072, N=1024
    hgemm_kernel<<<dim3(8, 128), dim3(256), 0, stream>>>(x_h, wkT, conv_b, cnn,
                                                         zp, 1024, 3072, 0, 0, 0, 0);
    // 3. LayerNorm -> nrm f32 (d_out) + nrm_h f16
    ln_kernel<<<dim3(16384), dim3(256), 0, stream>>>(cnn, ln_g, ln_b, nrm, nrm_h);
    // 4+5. L-chunked: proj GEMM (M=16*Lc, K=1024, N=3072) then scan chunk
    for (int l0 = 0; l0 < LL; l0 += Lc) {
        hgemm_kernel<<<dim3(24, 16 * tpb), dim3(256), 0, stream>>>(
            nrm_h, swT, nullptr, U_buf, zp, 3072, 1024, 1, l0, tpb, Lc);
        scan_kernel<<<dim3(256), dim3(64), 0, stream>>>(
            U_buf, nrm, cnn, sru_v, sru_b, lambda_w, out, c_state, l0, Lc);
    }
    // 6. in-place RMSNorm
    rms_kernel<<<dim3(16384), dim3(256), 0, stream>>>(out, rms_w);
}

// Round 7
// 553.702 us; speedup vs baseline: 5.0549x; 1.0830x over previous
//
#include <hip/hip_runtime.h>
#include <cstdint>
#include <cstddef>

#define LL 1024
#define DD 1024
#define BB 16

typedef _Float16 f16;
typedef _Float16 f16x8 __attribute__((ext_vector_type(8)));
typedef _Float16 f16x4 __attribute__((ext_vector_type(4)));
typedef float f32x4 __attribute__((ext_vector_type(4)));

// ---------------------------------------------------------------------------
// x (f32) -> x_h (f16), vectorized
// ---------------------------------------------------------------------------
__global__ __launch_bounds__(256) void xsplit_kernel(const float* __restrict__ x,
                                                     f16* __restrict__ xh) {
    int i = blockIdx.x * 256 + threadIdx.x;          // float4 index
    const int total = BB * LL * DD / 4;
    if (i >= total) return;
    float4 v = ((const float4*)x)[i];
    f16x4 h;
    h[0] = (f16)v.x; h[1] = (f16)v.y; h[2] = (f16)v.z; h[3] = (f16)v.w;
    ((f16x4*)xh)[i] = h;
}

// ---------------------------------------------------------------------------
// conv_w (O,I,K) -> wkT f16 [o][k*1024+i]. Within-row permutation: one block
// per o-row; coalesced read -> LDS -> permuted coalesced write.
// LDS read stride 3 (odd) => conflict-free.
// ---------------------------------------------------------------------------
__global__ __launch_bounds__(256) void wkt_kernel(const float* __restrict__ w,
                                                  f16* __restrict__ wkT) {
    __shared__ float s[3072];
    const int o = blockIdx.x;                        // 1024 blocks
    const int t = threadIdx.x;
    const float* src = w + (size_t)o * 3072;
#pragma unroll
    for (int rep = 0; rep < 12; ++rep) s[rep * 256 + t] = src[rep * 256 + t];
    __syncthreads();
    f16* dst = wkT + (size_t)o * 3072;
#pragma unroll
    for (int rep = 0; rep < 12; ++rep) {
        int j = rep * 256 + t;
        int k = j >> 10, i = j & 1023;
        dst[j] = (f16)s[i * 3 + k];
    }
}

// ---------------------------------------------------------------------------
// sru_w [D][3D] -> swT f16 [e][d]. True transpose via 64x64 LDS tile (+1 pad).
// grid (48 e-tiles, 16 d-tiles), 256 threads.
// ---------------------------------------------------------------------------
__global__ __launch_bounds__(256) void swt_kernel(const float* __restrict__ w,
                                                  f16* __restrict__ swT) {
    __shared__ float s[64][65];
    const int et = blockIdx.x, dt = blockIdx.y;
    const int t = threadIdx.x;
    const int tr = t >> 6, tc = t & 63;
#pragma unroll
    for (int i = 0; i < 16; ++i) {
        int d = dt * 64 + i * 4 + tr;
        s[i * 4 + tr][tc] = w[(size_t)d * 3072 + et * 64 + tc];
    }
    __syncthreads();
#pragma unroll
    for (int i = 0; i < 16; ++i) {
        int e = i * 4 + tr;
        swT[(size_t)(et * 64 + e) * 1024 + dt * 64 + tc] = (f16)s[tc][e];
    }
}

// ---------------------------------------------------------------------------
// Zero page for causal-pad rows (d_ws is poisoned 0xAA before every call).
// ---------------------------------------------------------------------------
__global__ __launch_bounds__(128) void zp_kernel(f16* __restrict__ zp) {
    zp[threadIdx.x] = (f16)0;                        // 128 f16 = 256 B
}

// ---------------------------------------------------------------------------
// f16 MFMA GEMM: C[M][N] = A[M][K] * BT[N][K]^T (+bias), 128x128 tile, BK=64,
// 4 waves x (64x64), v_mfma_f32_16x16x32_f16, global_load_lds dwordx4 staging,
// LDS double-buffered, XOR bank-swizzle via pre-swizzled global source
// (rule #21). One vmcnt(0)+barrier per K-tile (2-phase T3-minimum).
//
// XCD swizzle (T1): 1D grid, id -> r=id&7 (XCD), s=id>>3; bx=s%nx,
// by=(s/nx)*8+r. Consecutive blocks on one XCD share the A row-panel ->
// A fetched ~once per XCD instead of 8x. Bijective (ny % 8 == 0 for all Lc).
//
// MODE 0 (conv): A = x_h (B,L,D), causal shift t=l+kc-2, t<0 rows read the
//   zero page. C f32 + bias. MODE 1 (proj): L-chunked rows, C f16, no bias.
// MFMA layouts: A lane l supplies A[row=l&15][k=(l>>4)*8+e]; B symmetric;
// C/D lane l reg r -> row=(l>>4)*4+r, col=l&15 (m89-verified).
// ---------------------------------------------------------------------------
template <int MODE, int NN, int KK, bool OUTF16>
__global__ __launch_bounds__(256) void hgemm_kernel(
    const f16* __restrict__ A, const f16* __restrict__ BT,
    const float* __restrict__ bias, void* __restrict__ Cv,
    const f16* __restrict__ zp, int l0, int tpb, int Lc) {
    __shared__ f16 sm[2][2][128 * 64];               // [buf][A/B][row*64 + e]
    const int tid = threadIdx.x;
    const int lane = tid & 63, wave = tid >> 6;
    const int wm = wave & 1, wn = wave >> 1;
    constexpr int nx = NN / 128;

    const int id = blockIdx.x;
    const int r8 = id & 7, s = id >> 3;
    const int bx = s % nx;
    const int by = (s / nx) * 8 + r8;
    const int n0 = bx * 128;

    int arowbase, crowbase;
    if (MODE == 0) {
        arowbase = by * 128;
        crowbase = arowbase;
    } else {
        int bb = by / tpb, lt = by - bb * tpb;
        arowbase = (bb << 10) + l0 + lt * 128;
        crowbase = bb * Lc + lt * 128;
    }

    // staging: instr i covers rows wave*32+i*8..+8; lane -> row=base+(lane>>3),
    // chunk=(lane&7)^(row&7) so after the linear LDS write,
    // lds[row][c] = global[row][c ^ (row&7)].
    auto stageA = [&](int kt, int buf) {
#pragma unroll
        for (int i = 0; i < 4; ++i) {
            int row = wave * 32 + i * 8 + (lane >> 3);
            int chunk = (lane & 7) ^ (row & 7);
            const f16* src;
            if (MODE == 0) {
                int m = arowbase + row;
                int bb2 = m >> 10, l = m & 1023;
                int kc = kt >> 10;
                int t = l + kc - 2;                   // causal shift
                src = (t < 0) ? (zp + chunk * 8)
                              : (A + (((size_t)(bb2 << 10) + t) << 10) +
                                 (kt & 1023) + chunk * 8);
            } else {
                src = A + ((size_t)(arowbase + row) << 10) + kt + chunk * 8;
            }
            __builtin_amdgcn_global_load_lds(
                (const __attribute__((address_space(1))) void*)src,
                (__attribute__((address_space(3))) void*)&sm[buf][0][(wave * 32 + i * 8) * 64],
                16, 0, 0);
        }
    };
    auto stageB = [&](int kt, int buf) {
#pragma unroll
        for (int i = 0; i < 4; ++i) {
            int row = wave * 32 + i * 8 + (lane >> 3);
            int chunk = (lane & 7) ^ (row & 7);
            const f16* src = BT + (size_t)(n0 + row) * KK + kt + chunk * 8;
            __builtin_amdgcn_global_load_lds(
                (const __attribute__((address_space(1))) void*)src,
                (__attribute__((address_space(3))) void*)&sm[buf][1][(wave * 32 + i * 8) * 64],
                16, 0, 0);
        }
    };

    f32x4 acc[4][4];
#pragma unroll
    for (int i = 0; i < 4; ++i)
#pragma unroll
        for (int j = 0; j < 4; ++j)
#pragma unroll
            for (int r = 0; r < 4; ++r) acc[i][j][r] = 0.f;

    stageA(0, 0);
    stageB(0, 0);
    asm volatile("s_waitcnt vmcnt(0)" ::: "memory");
    __syncthreads();

    const int kbyte = (lane >> 4) * 16;
    const int rA = wm * 64 + (lane & 15);
    const int rB = wn * 64 + (lane & 15);

    int cur = 0;
    for (int kt = 0; kt < KK; kt += 64) {
        if (kt + 64 < KK) {                          // overlap staging w/ MFMA
            stageA(kt + 64, cur ^ 1);
            stageB(kt + 64, cur ^ 1);
        }
        const char* Ap = (const char*)&sm[cur][0][0];
        const char* Bp = (const char*)&sm[cur][1][0];
#pragma unroll
        for (int ks = 0; ks < 2; ++ks) {
            f16x8 a[4], b[4];
#pragma unroll
            for (int f = 0; f < 4; ++f) {
                int rowa = rA + f * 16;
                a[f] = *(const f16x8*)(Ap + rowa * 128 +
                                       ((ks * 64 + kbyte) ^ ((rowa & 7) << 4)));
                int rowb = rB + f * 16;
                b[f] = *(const f16x8*)(Bp + rowb * 128 +
                                       ((ks * 64 + kbyte) ^ ((rowb & 7) << 4)));
            }
#pragma unroll
            for (int fi = 0; fi < 4; ++fi)
#pragma unroll
                for (int fj = 0; fj < 4; ++fj)
                    acc[fi][fj] = __builtin_amdgcn_mfma_f32_16x16x32_f16(
                        a[fi], b[fj], acc[fi][fj], 0, 0, 0);
        }
        asm volatile("s_waitcnt vmcnt(0)" ::: "memory");
        __syncthreads();
        cur ^= 1;
    }

    // epilogue: C/D layout col=lane&15, row=(lane>>4)*4+r
    float bv[4];
#pragma unroll
    for (int fj = 0; fj < 4; ++fj)
        bv[fj] = (!OUTF16 && bias) ? bias[n0 + wn * 64 + fj * 16 + (lane & 15)] : 0.f;
#pragma unroll
    for (int fi = 0; fi < 4; ++fi) {
        int row0 = crowbase + wm * 64 + fi * 16 + ((lane >> 4) << 2);
#pragma unroll
        for (int fj = 0; fj < 4; ++fj) {
            int col = n0 + wn * 64 + fj * 16 + (lane & 15);
            if (OUTF16) {
                f16* cp = (f16*)Cv + (size_t)row0 * NN + col;
#pragma unroll
                for (int r = 0; r < 4; ++r)
                    cp[(size_t)r * NN] = (f16)acc[fi][fj][r];
            } else {
                float* cp = (float*)Cv + (size_t)row0 * NN + col;
#pragma unroll
                for (int r = 0; r < 4; ++r)
                    cp[(size_t)r * NN] = acc[fi][fj][r] + bv[fj];
            }
        }
    }
}

// ---------------------------------------------------------------------------
// LayerNorm over D=1024 -> f16 only (nobody consumes the f32 copy anymore).
// One block (256 threads, float4 each) per row.
// ---------------------------------------------------------------------------
__global__ __launch_bounds__(256) void ln_kernel(const float* __restrict__ in,
                                                 const float* __restrict__ g,
                                                 const float* __restrict__ be,
                                                 f16* __restrict__ outh) {
    const int m = blockIdx.x;
    const int t = threadIdx.x;
    const float4 v = ((const float4*)(in + ((size_t)m << 10)))[t];
    float s = v.x + v.y + v.z + v.w;
    float q = v.x * v.x + v.y * v.y + v.z * v.z + v.w * v.w;
#pragma unroll
    for (int off = 32; off; off >>= 1) {
        s += __shfl_down(s, off);
        q += __shfl_down(q, off);
    }
    __shared__ float red[8];
    const int wv = t >> 6, ln = t & 63;
    if (ln == 0) { red[wv] = s; red[4 + wv] = q; }
    __syncthreads();
    float S = red[0] + red[1] + red[2] + red[3];
    float Q = red[4] + red[5] + red[6] + red[7];
    float mu  = S * (1.f / 1024.f);
    float var = Q * (1.f / 1024.f) - mu * mu;
    float inv = rsqrtf(var + 1e-5f);
    float4 g4  = ((const float4*)g)[t];
    float4 b4  = ((const float4*)be)[t];
    f16x4 h;
    h[0] = (f16)((v.x - mu) * inv * g4.x + b4.x);
    h[1] = (f16)((v.y - mu) * inv * g4.y + b4.y);
    h[2] = (f16)((v.z - mu) * inv * g4.z + b4.z);
    h[3] = (f16)((v.w - mu) * inv * g4.w + b4.w);
    ((f16x4*)(outh + ((size_t)m << 10)))[t] = h;
}

// ---------------------------------------------------------------------------
// SRU scan over one L-chunk [l0, l0+Lc). 16384 independent (b,d) recurrences;
// 256 blocks x 64 threads. Carry persisted in c_state. 8-deep double-buffered
// register prefetch. U and nrm are f16; cnn stays f32 (dominant mix term).
// Fuses lambda mix: out = lw*cnn + (1-lw)*h  (f32 -> d_out).
// ---------------------------------------------------------------------------
__device__ __forceinline__ float sigmoid_f(float x) {
    return __builtin_amdgcn_rcpf(1.f + __expf(-x));
}
__device__ __forceinline__ float tanh_f(float x) {
    float e = __expf(2.f * x);                     // inf for large x -> t = 1
    return 1.f - 2.f * __builtin_amdgcn_rcpf(e + 1.f);
}

__global__ __launch_bounds__(64) void scan_kernel(const f16* __restrict__ U,
                                                  const f16* __restrict__ nrm_h,
                                                  const float* __restrict__ cnn,
                                                  const float* __restrict__ v_in,
                                                  const float* __restrict__ b_in,
                                                  const float* __restrict__ lam,
                                                  float* __restrict__ outp,
                                                  float* __restrict__ c_state,
                                                  int l0, int Lc) {
    const int tid = blockIdx.x * 64 + threadIdx.x;   // 0..16383
    const int b = tid >> 10, d = tid & 1023;
    const float vf = v_in[d], vr = v_in[DD + d];
    const float bf = b_in[d], br = b_in[DD + d];
    const float lw = lam[d];
    const f16* Up = U + (size_t)b * Lc * 3072 + 3 * d;         // chunk-local rows
    const size_t rowbase = (((size_t)(b << 10) + l0) << 10) + d;
    const f16*   xp = nrm_h + rowbase;
    const float* cp = cnn + rowbase;
    float*       op = outp + rowbase;

    float c = (l0 == 0) ? 0.f : c_state[tid];
    constexpr int CH = 8;
    float A0[CH], A1[CH], A2[CH], AX[CH], AC[CH];
    float B0[CH], B1[CH], B2[CH], BX[CH], BC[CH];

#pragma unroll
    for (int j = 0; j < CH; ++j) {
        size_t lu = (size_t)j * 3072, lx = (size_t)j << 10;
        A0[j] = (float)Up[lu]; A1[j] = (float)Up[lu + 1]; A2[j] = (float)Up[lu + 2];
        AX[j] = (float)xp[lx]; AC[j] = cp[lx];
    }

    for (int ll0 = 0; ll0 < Lc; ll0 += 2 * CH) {
#pragma unroll
        for (int j = 0; j < CH; ++j) {
            int ll = ll0 + CH + j;
            size_t lu = (size_t)ll * 3072, lx = (size_t)ll << 10;
            B0[j] = (float)Up[lu]; B1[j] = (float)Up[lu + 1]; B2[j] = (float)Up[lu + 2];
            BX[j] = (float)xp[lx]; BC[j] = cp[lx];
        }
#pragma unroll
        for (int j = 0; j < CH; ++j) {
            float f = sigmoid_f(A1[j] + vf * c + bf);
            float r = sigmoid_f(A2[j] + vr * c + br);
            float cn = fmaf(f, c - A0[j], A0[j]);        // f*c + (1-f)*u0
            float h  = r * tanh_f(cn) + (1.f - r) * AX[j];
            c = cn;
            op[(size_t)(ll0 + j) << 10] = fmaf(lw, AC[j] - h, h);
        }
        if (ll0 + 2 * CH < Lc) {
#pragma unroll
            for (int j = 0; j < CH; ++j) {
                int ll = ll0 + 2 * CH + j;
                size_t lu = (size_t)ll * 3072, lx = (size_t)ll << 10;
                A0[j] = (float)Up[lu]; A1[j] = (float)Up[lu + 1]; A2[j] = (float)Up[lu + 2];
                AX[j] = (float)xp[lx]; AC[j] = cp[lx];
            }
        }
#pragma unroll
        for (int j = 0; j < CH; ++j) {
            float f = sigmoid_f(B1[j] + vf * c + bf);
            float r = sigmoid_f(B2[j] + vr * c + br);
            float cn = fmaf(f, c - B0[j], B0[j]);
            float h  = r * tanh_f(cn) + (1.f - r) * BX[j];
            c = cn;
            op[(size_t)(ll0 + CH + j) << 10] = fmaf(lw, BC[j] - h, h);
        }
    }
    c_state[tid] = c;
}

// ---------------------------------------------------------------------------
// In-place RMSNorm over D=1024 on d_out.
// ---------------------------------------------------------------------------
__global__ __launch_bounds__(256) void rms_kernel(float* __restrict__ io,
                                                  const float* __restrict__ w) {
    const int m = blockIdx.x;
    const int t = threadIdx.x;
    float4 v = ((float4*)(io + ((size_t)m << 10)))[t];
    float q = v.x * v.x + v.y * v.y + v.z * v.z + v.w * v.w;
#pragma unroll
    for (int off = 32; off; off >>= 1) q += __shfl_down(q, off);
    __shared__ float red[4];
    const int wv = t >> 6, ln = t & 63;
    if (ln == 0) red[wv] = q;
    __syncthreads();
    float Q = red[0] + red[1] + red[2] + red[3];
    float inv = rsqrtf(Q * (1.f / 1024.f) + 1e-6f);
    float4 w4 = ((const float4*)w)[t];
    v.x *= inv * w4.x;
    v.y *= inv * w4.y;
    v.z *= inv * w4.z;
    v.w *= inv * w4.w;
    ((float4*)(io + ((size_t)m << 10)))[t] = v;
}

// ---------------------------------------------------------------------------
// Workspace layout (f16 elements unless noted):
//   x_h 16M | nrm_h 16M | wkT 3M | swT 3M | zp 1K | U_h 16*Lc*3072
//   then f32: cnn 16M | c_state 16K
// Lc=1024 -> ~236 MB total (ws_size known >= ~348 MB from round 5).
// ---------------------------------------------------------------------------
extern "C" void kernel_launch(void* const* d_in, const int* in_sizes, int n_in,
                              void* d_out, int out_size, void* d_ws, size_t ws_size,
                              hipStream_t stream) {
    const float* x        = (const float*)d_in[0];
    const float* conv_w   = (const float*)d_in[1];
    const float* conv_b   = (const float*)d_in[2];
    const float* ln_g     = (const float*)d_in[3];
    const float* ln_b     = (const float*)d_in[4];
    const float* sru_w    = (const float*)d_in[5];
    const float* sru_v    = (const float*)d_in[6];
    const float* sru_b    = (const float*)d_in[7];
    const float* lambda_w = (const float*)d_in[8];
    const float* rms_w    = (const float*)d_in[9];
    float* out = (float*)d_out;

    const size_t fixed_f16 = (size_t)38 * 1024 * 1024 + 1024;   // x_h,nrm_h,wkT,swT,zp
    const size_t f32_bytes = ((size_t)16 * 1024 * 1024 + 16384) * 4;
    int Lc = 128;
    for (int cand = 1024; cand >= 128; cand >>= 1) {
        if (fixed_f16 * 2 + (size_t)16 * cand * 3072 * 2 + f32_bytes <= ws_size) {
            Lc = cand; break;
        }
    }
    const int tpb = Lc / 128;

    f16* x_h   = (f16*)d_ws;                              // 16M f16
    f16* nrm_h = x_h   + (size_t)16 * 1024 * 1024;        // 16M f16
    f16* wkT   = nrm_h + (size_t)16 * 1024 * 1024;        // 3M f16
    f16* swT   = wkT   + (size_t)3 * 1024 * 1024;         // 3M f16
    f16* zp    = swT   + (size_t)3 * 1024 * 1024;         // 1K f16 (zero page)
    f16* U_h   = zp + 1024;                               // 16*Lc*3072 f16
    float* cnn     = (float*)(U_h + (size_t)16 * Lc * 3072);   // 16M f32
    float* c_state = cnn + (size_t)16 * 1024 * 1024;      // 16K f32

    // 1. prep
    xsplit_kernel<<<dim3(16384), dim3(256), 0, stream>>>(x, x_h);
    wkt_kernel<<<dim3(1024), dim3(256), 0, stream>>>(conv_w, wkT);
    swt_kernel<<<dim3(48, 16), dim3(256), 0, stream>>>(sru_w, swT);
    zp_kernel<<<dim3(1), dim3(128), 0, stream>>>(zp);
    // 2. conv GEMM (causal pad fused): M=16384, K=3072, N=1024, f32 out + bias
    hgemm_kernel<0, 1024, 3072, false>
        <<<dim3(8 * 128), dim3(256), 0, stream>>>(x_h, wkT, conv_b, cnn, zp, 0, 0, 0);
    // 3. LayerNorm -> nrm_h (f16 only)
    ln_kernel<<<dim3(16384), dim3(256), 0, stream>>>(cnn, ln_g, ln_b, nrm_h);
    // 4+5. L-chunked: proj GEMM (M=16*Lc, K=1024, N=3072, f16 out) then scan
    for (int l0 = 0; l0 < LL; l0 += Lc) {
        hgemm_kernel<1, 3072, 1024, true>
            <<<dim3(24 * 16 * tpb), dim3(256), 0, stream>>>(
                nrm_h, swT, nullptr, U_h, zp, l0, tpb, Lc);
        scan_kernel<<<dim3(256), dim3(64), 0, stream>>>(
            U_h, nrm_h, cnn, sru_v, sru_b, lambda_w, out, c_state, l0, Lc);
    }
    // 6. in-place RMSNorm
    rms_kernel<<<dim3(16384), dim3(256), 0, stream>>>(out, rms_w);
}